// Round 10
// baseline (203.321 us; speedup 1.0000x reference)
//
#include <hip/hip_runtime.h>

#define NBH 32      // B*H
#define LL  2048
#define DD  64
#define BQ  64      // q rows per block
#define BK  64      // k tile
#define NT  32      // LL/BK
#define CSHIFT 120.0f

typedef _Float16 f16;
typedef _Float16 f16x4 __attribute__((ext_vector_type(4)));
typedef _Float16 f16x8 __attribute__((ext_vector_type(8)));
typedef _Float16 f16x8a __attribute__((ext_vector_type(8), may_alias));
typedef _Float16 f16x4a __attribute__((ext_vector_type(4), may_alias));
typedef float f32x4 __attribute__((ext_vector_type(4)));

#define SBARR() __builtin_amdgcn_sched_barrier(0)
#define BARRIER() do { SBARR(); __builtin_amdgcn_s_barrier(); SBARR(); } while (0)
#define WAITVM(N) do { SBARR(); asm volatile("s_waitcnt vmcnt(" #N ")" ::: "memory"); SBARR(); } while (0)

__device__ __forceinline__ float elu1(float x) { return x > 0.f ? x + 1.f : __expf(x); }

__device__ __forceinline__ void gl_lds16(const void* src, void* lds_dst) {
  __builtin_amdgcn_global_load_lds((const __attribute__((address_space(1))) unsigned int*)src,
                                   (__attribute__((address_space(3))) unsigned int*)lds_dst,
                                   16, 0, 0);
}

// Stage a 64-row x 128B tile into 8KB LDS (linear dest, 2 gl_lds per thread).
// Content swizzled: LDS 16B-slot s of row r holds global slot s^(r&7).
__device__ __forceinline__ void stage_tile(const char* gbase, size_t grow, f16* lds, int w, int l) {
#pragma unroll
  for (int c2 = 0; c2 < 2; ++c2) {
    int U = w * 128 + c2 * 64 + l;       // 16B unit id
    int r = U >> 3, sp = U & 7;
    gl_lds16(gbase + (size_t)r * grow + ((sp ^ (r & 7)) << 4),
             (char*)lds + w * 2048 + c2 * 1024);   // wave-uniform base; HW adds lane*16
  }
}

// Featurize K -> fp16 and transpose V -> Vt[d][k] fp16, one read pass.
__global__ void prep(const float* __restrict__ K, const float* __restrict__ V,
                     f16* __restrict__ Kf, f16* __restrict__ Vt) {
  __shared__ f16 Lt[64][72];
  const int bh = blockIdx.y, r0 = blockIdx.x * 64;
  const int t = threadIdx.x;
#pragma unroll
  for (int it = 0; it < 4; ++it) {
    int idx = t + 256 * it;
    int r = idx >> 4, d0 = (idx & 15) * 4;
    float4 kv = *(const float4*)(K + (size_t)(bh * LL + r0 + r) * DD + d0);
    f16x4 kh = { (f16)elu1(kv.x), (f16)elu1(kv.y), (f16)elu1(kv.z), (f16)elu1(kv.w) };
    *(f16x4a*)(Kf + (size_t)(bh * LL + r0 + r) * DD + d0) = kh;
    float4 vv = *(const float4*)(V + (size_t)(bh * LL + r0 + r) * DD + d0);
    f16x4 vh = { (f16)vv.x, (f16)vv.y, (f16)vv.z, (f16)vv.w };
    *(f16x4a*)&Lt[r][d0] = vh;
  }
  __syncthreads();
  const int w = t >> 6, l = t & 63;
#pragma unroll
  for (int it = 0; it < 2; ++it) {
    int s = w + 4 * it;
    f16x8 o;
#pragma unroll
    for (int j = 0; j < 8; ++j) o[j] = Lt[8 * s + j][l];
    *(f16x8*)(Vt + (size_t)(bh * DD + l) * LL + r0 + 8 * s) = o;
  }
}

// R9 structure + XCD-aware block swizzle (T1): HW assigns XCD = wgid%8, so
// bh = (id&7)*4 + ((id>>3)&3) pins 4 heads per XCD -> Kf/Vt working set
// 2MB/XCD stays L2-resident for all staging reads (was 16MB -> thrash -> L3).
// nt stores bypass L2, leaving it entirely for the staged reads.
//   QK: acc = mfma(Kfrag, Qfrag) -> lane holds s[k=16n+4g+i][q=16w+c]
//   PV: ctx = mfma(Vfrag, Pfrag) -> lane holds ctx[d=16n+4g+i][q=16w+c]
__launch_bounds__(256, 4)
__global__ void attn_fused(const float* __restrict__ Q, const f16* __restrict__ Kf,
                           const f16* __restrict__ Vt,
                           float* __restrict__ ctx_out, float* __restrict__ attn_out) {
  __shared__ f16 KV[4][BK * DD];  // loop1: 4-slot K ring; loop2: [0,1]=K dbuf, [2,3]=V dbuf
  __shared__ f16 Pf[BQ * BK];     // [q][k] fp16, 16B-slot swizzle phys = slot^(q&7)
  const int id = blockIdx.x;
  const int bh = (id & 7) * 4 + ((id >> 3) & 3);   // XCD (=id%8) owns heads 4x..4x+3
  const int q0 = (id >> 5) * BQ;
  const int t = threadIdx.x, w = t >> 6, l = t & 63, g = l >> 4, c = l & 15;
  const char* Kh  = (const char*)(Kf + (size_t)bh * LL * DD);
  const char* Vth = (const char*)(Vt + (size_t)bh * DD * LL);
  float* __restrict__ attn_h = attn_out + (size_t)bh * LL * LL;

  // Q fragments from global, featurized in-reg. Lane holds Q[16w+c][32ka+8g+j].
  const int qrow = q0 + 16 * w + c;
  f16x8 qf[2];
#pragma unroll
  for (int ka = 0; ka < 2; ++ka) {
    const float* qp = Q + (size_t)(bh * LL + qrow) * DD + 32 * ka + 8 * g;
    float4 a = *(const float4*)qp;
    float4 b = *(const float4*)(qp + 4);
    f16x8 h = { (f16)elu1(a.x), (f16)elu1(a.y), (f16)elu1(a.z), (f16)elu1(a.w),
                (f16)elu1(b.x), (f16)elu1(b.y), (f16)elu1(b.z), (f16)elu1(b.w) };
    qf[ka] = h;
  }

  float rs = 0.f;
  auto rowsum_tile = [&](const f16* KbT) {
    const char* Kb = (const char*)KbT;
#pragma unroll
    for (int n = 0; n < 4; ++n) {
      f32x4 acc = {0.f, 0.f, 0.f, 0.f};
#pragma unroll
      for (int ka = 0; ka < 2; ++ka) {
        int row = n * 16 + c;
        f16x8 kfr = (f16x8)(*(const f16x8a*)(Kb + row * 128 + (((4 * ka + g) ^ (row & 7)) << 4)));
        acc = __builtin_amdgcn_mfma_f32_16x16x32_f16(kfr, qf[ka], acc, 0, 0, 0);
      }
#pragma unroll
      for (int i = 0; i < 4; ++i) rs += __expf(acc[i] - CSHIFT);
    }
  };

  // ============ loop 1: rowsums (4-deep ring, 1 barrier/tile) ============
  stage_tile(Kh, 128, KV[0], w, l);
  stage_tile(Kh + (size_t)BK * 128, 128, KV[1], w, l);
  for (int kt = 0; kt < NT - 2; ++kt) {
    stage_tile(Kh + (size_t)(kt + 2) * BK * 128, 128, KV[(kt + 2) & 3], w, l);
    WAITVM(4);        // L_kt landed (L_{kt+1}, L_{kt+2} = 4 may remain)
    BARRIER();        // everyone's L_kt landed; everyone finished tile kt-1
    rowsum_tile(KV[kt & 3]);
  }
  WAITVM(2); BARRIER(); rowsum_tile(KV[(NT - 2) & 3]);   // kt=30
  WAITVM(0); BARRIER(); rowsum_tile(KV[(NT - 1) & 3]);   // kt=31

  rs += __shfl_xor(rs, 16);
  rs += __shfl_xor(rs, 32);
  const float inv = 1.0f / rs;

  f32x4 ctx[4];
#pragma unroll
  for (int n = 0; n < 4; ++n) ctx[n] = (f32x4){0.f, 0.f, 0.f, 0.f};

  auto main_tile = [&](int kt, const f16* KbT, const f16* VbT) {
    const char* Kb = (const char*)KbT;
    const char* Vb = (const char*)VbT;
#pragma unroll
    for (int n = 0; n < 4; ++n) {
      f32x4 acc = {0.f, 0.f, 0.f, 0.f};
#pragma unroll
      for (int ka = 0; ka < 2; ++ka) {
        int row = n * 16 + c;
        f16x8 kfr = (f16x8)(*(const f16x8a*)(Kb + row * 128 + (((4 * ka + g) ^ (row & 7)) << 4)));
        acc = __builtin_amdgcn_mfma_f32_16x16x32_f16(kfr, qf[ka], acc, 0, 0, 0);
      }
      f32x4 p;
#pragma unroll
      for (int i = 0; i < 4; ++i) p[i] = __expf(acc[i] - CSHIFT) * inv;  // normalized
      f16x4 ph = { (f16)p[0], (f16)p[1], (f16)p[2], (f16)p[3] };
      int slot = (2 * n + (g >> 1)) ^ (c & 7);
      *(f16x4a*)((char*)Pf + (16 * w + c) * 128 + slot * 16 + (g & 1) * 8) = ph;
    }
    // PV: A-frag from Vs, B-frag from Pf (wave-local rows; lgkm-ordered)
#pragma unroll
    for (int ka = 0; ka < 2; ++ka) {
      f16x8 pf = (f16x8)(*(const f16x8a*)((const char*)Pf + (16 * w + c) * 128 + (((4 * ka + g) ^ (c & 7)) << 4)));
#pragma unroll
      for (int n = 0; n < 4; ++n) {
        int row = n * 16 + c;
        f16x8 vf = (f16x8)(*(const f16x8a*)(Vb + row * 128 + (((4 * ka + g) ^ (row & 7)) << 4)));
        ctx[n] = __builtin_amdgcn_mfma_f32_16x16x32_f16(vf, pf, ctx[n], 0, 0, 0);
      }
    }
    // attn store: b64 LDS read + cvt + nt f32x4; wave covers 4 full rows/inst
    float* abase = attn_h + (size_t)q0 * LL + kt * BK;
#pragma unroll
    for (int it = 0; it < 4; ++it) {
      int r_loc = 16 * w + 4 * it + (l >> 4);
      int u = l & 15;
      int phys = (((u >> 1) ^ (r_loc & 7)) << 4) + (u & 1) * 8;
      f16x4 hv = *(const f16x4a*)((const char*)Pf + r_loc * 128 + phys);
      f32x4 sv = { (float)hv[0], (float)hv[1], (float)hv[2], (float)hv[3] };
      __builtin_nontemporal_store(sv, (f32x4*)(abase + (size_t)r_loc * LL + 4 * u));
    }
  };

  // ============ loop 2: recompute + attn + PV (dbuf, 2 barriers) ============
  WAITVM(0);
  BARRIER();          // all loop1 reads done -> slots reusable
  stage_tile(Kh, 128, KV[0], w, l);
  stage_tile(Vth, (size_t)LL * 2, KV[2], w, l);
  stage_tile(Kh + (size_t)BK * 128, 128, KV[1], w, l);
  stage_tile(Vth + (size_t)BK * 2, (size_t)LL * 2, KV[3], w, l);
  WAITVM(4);          // K0,V0 landed; K1,V1 in flight
  BARRIER();
  main_tile(0, KV[0], KV[2]);   // issues S_0 (4 nt stores/wave)
  BARRIER();
  for (int kt = 1; kt < NT - 1; ++kt) {
    stage_tile(Kh + (size_t)(kt + 1) * BK * 128, 128, KV[(kt + 1) & 1], w, l);
    stage_tile(Vth + (size_t)(kt + 1) * BK * 2, (size_t)LL * 2, KV[2 + ((kt + 1) & 1)], w, l);
    WAITVM(8);        // queue [L_kt(4), S_{kt-1}(4), L_{kt+1}(4)] -> L_kt landed
    BARRIER();
    main_tile(kt, KV[kt & 1], KV[2 + (kt & 1)]);
    BARRIER();
  }
  WAITVM(4);          // queue [L_31(4), S_30(4)] -> L_31 landed
  BARRIER();
  main_tile(NT - 1, KV[1], KV[3]);

#pragma unroll
  for (int n = 0; n < 4; ++n)
    *(f32x4*)(ctx_out + (size_t)(bh * LL + qrow) * DD + n * 16 + 4 * g) = ctx[n];
}

extern "C" void kernel_launch(void* const* d_in, const int* in_sizes, int n_in,
                              void* d_out, int out_size, void* d_ws, size_t ws_size,
                              hipStream_t stream) {
  const float* Q = (const float*)d_in[0];
  const float* K = (const float*)d_in[1];
  const float* V = (const float*)d_in[2];

  float* ctx_out  = (float*)d_out;                      // [32][2048][64]
  float* attn_out = ctx_out + (size_t)NBH * LL * DD;    // [32][2048][2048]

  f16* Kf = (f16*)d_ws;                                 // featurized K, fp16, 8 MB
  f16* Vt = Kf + (size_t)NBH * LL * DD;                 // V^T per head, fp16, 8 MB

  hipLaunchKernelGGL(prep, dim3(LL / 64, NBH), dim3(256), 0, stream, K, V, Kf, Vt);
  hipLaunchKernelGGL(attn_fused, dim3(LL / BQ * NBH), dim3(256), 0, stream,
                     Q, Kf, Vt, ctx_out, attn_out);
}

// Round 11
// 159.415 us; speedup vs baseline: 1.2754x; 1.2754x over previous
//
#include <hip/hip_runtime.h>

#define NBH 32      // B*H
#define LL  2048
#define DD  64
#define BQ  64      // q rows per block
#define BK  64      // k tile
#define NT  32      // LL/BK
#define CSHIFT 120.0f

typedef _Float16 f16;
typedef _Float16 f16x4 __attribute__((ext_vector_type(4)));
typedef _Float16 f16x8 __attribute__((ext_vector_type(8)));
typedef _Float16 f16x8a __attribute__((ext_vector_type(8), may_alias));
typedef _Float16 f16x4a __attribute__((ext_vector_type(4), may_alias));
typedef float f32x4 __attribute__((ext_vector_type(4)));

__device__ __forceinline__ float elu1(float x) { return x > 0.f ? x + 1.f : __expf(x); }

// prep: featurize K, transpose V, and emit BOTH in fragment-major layout:
// 1KB block per (kt, n, ka); lane l's 16B at blockbase + l*16 equals exactly
// the bytes the old swizzled-LDS fragment read returned:
//   K block: K[kt*64 + 16n + (l&15)][32ka + 8*(l>>4) .. +7]   (elu1, f16)
//   V block: V^T[16n + (l&15)][kt*64 + 32ka + 8*(l>>4) .. +7] (f16)
__global__ void prep(const float* __restrict__ K, const float* __restrict__ V,
                     f16* __restrict__ Kfg, f16* __restrict__ Vfg) {
  __shared__ f16 Ltk[64][72];   // featurized K rows [k][d]
  __shared__ f16 Ltv[64][72];   // V rows [k][d]
  __shared__ f16 VtL[64][72];   // V transposed [d][k]
  const int bh = blockIdx.y, kt = blockIdx.x, r0 = kt * 64;
  const int t = threadIdx.x;
#pragma unroll
  for (int it = 0; it < 4; ++it) {
    int idx = t + 256 * it;
    int r = idx >> 4, d0 = (idx & 15) * 4;
    float4 kv = *(const float4*)(K + (size_t)(bh * LL + r0 + r) * DD + d0);
    f16x4 kh = { (f16)elu1(kv.x), (f16)elu1(kv.y), (f16)elu1(kv.z), (f16)elu1(kv.w) };
    *(f16x4a*)&Ltk[r][d0] = kh;
    float4 vv = *(const float4*)(V + (size_t)(bh * LL + r0 + r) * DD + d0);
    f16x4 vh = { (f16)vv.x, (f16)vv.y, (f16)vv.z, (f16)vv.w };
    *(f16x4a*)&Ltv[r][d0] = vh;
  }
  __syncthreads();
  const int w = t >> 6, l = t & 63;
#pragma unroll
  for (int it = 0; it < 2; ++it) {
    int s = w + 4 * it;
    f16x8 o;
#pragma unroll
    for (int j = 0; j < 8; ++j) o[j] = Ltv[8 * s + j][l];
    *(f16x8a*)&VtL[l][8 * s] = o;
  }
  __syncthreads();
  const int c = l & 15, g = l >> 4;
  char* kdst = (char*)Kfg + ((size_t)bh << 18) + ((size_t)kt << 13);
  char* vdst = (char*)Vfg + ((size_t)bh << 18) + ((size_t)kt << 13);
#pragma unroll
  for (int p = 0; p < 2; ++p) {
    int fb = w + 4 * p;                 // 0..7 = n*2+ka
    int n = fb >> 1, ka = fb & 1;
    f16x8 kf = *(const f16x8a*)&Ltk[16 * n + c][32 * ka + 8 * g];
    *(f16x8*)(kdst + (fb << 10) + l * 16) = kf;
    f16x8 vf = *(const f16x8a*)&VtL[16 * n + c][32 * ka + 8 * g];
    *(f16x8*)(vdst + (fb << 10) + l * 16) = vf;
  }
}

// Zero barriers, zero staging LDS. All K/V MFMA fragments are single coalesced
// b128 global loads from the fragment-major buffers (L2-resident; all 4 waves
// of a block read identical addresses -> L1 broadcast). Only Pf (8KB,
// wave-private rows) remains in LDS for the P transpose feeding PV and the
// full-line nt attn stores (R3/R4/R5 lessons).
//   QK: acc = mfma(Kfrag, Qfrag) -> lane holds s[k=16n+4g+i][q=16w+c]
//   PV: ctx = mfma(Vfrag, Pfrag) -> lane holds ctx[d=16n+4g+i][q=16w+c]
__launch_bounds__(256, 3)
__global__ void attn_fused(const float* __restrict__ Q, const f16* __restrict__ Kfg,
                           const f16* __restrict__ Vfg,
                           float* __restrict__ ctx_out, float* __restrict__ attn_out) {
  __shared__ f16 Pf[BQ * BK];   // [q][k] fp16, 16B-slot swizzle phys = slot^(q&7)
  const int bh = blockIdx.y, q0 = blockIdx.x * BQ;
  const int t = threadIdx.x, w = t >> 6, l = t & 63, g = l >> 4, c = l & 15;
  const char* Kh = (const char*)Kfg + ((size_t)bh << 18);
  const char* Vh = (const char*)Vfg + ((size_t)bh << 18);
  float* __restrict__ attn_h = attn_out + (size_t)bh * LL * LL;

  // Q fragments from global, featurized in-reg. Lane holds Q[16w+c][32ka+8g+j].
  const int qrow = q0 + 16 * w + c;
  f16x8 qf[2];
#pragma unroll
  for (int ka = 0; ka < 2; ++ka) {
    const float* qp = Q + (size_t)(bh * LL + qrow) * DD + 32 * ka + 8 * g;
    float4 a = *(const float4*)qp;
    float4 b = *(const float4*)(qp + 4);
    f16x8 h = { (f16)elu1(a.x), (f16)elu1(a.y), (f16)elu1(a.z), (f16)elu1(a.w),
                (f16)elu1(b.x), (f16)elu1(b.y), (f16)elu1(b.z), (f16)elu1(b.w) };
    qf[ka] = h;
  }

  // ================= loop 1: rowsums (free-running) =================
  float rs = 0.f;
#pragma unroll 2
  for (int kt = 0; kt < NT; ++kt) {
    const char* kb = Kh + ((size_t)kt << 13);
#pragma unroll
    for (int n = 0; n < 4; ++n) {
      f32x4 acc = {0.f, 0.f, 0.f, 0.f};
#pragma unroll
      for (int ka = 0; ka < 2; ++ka) {
        f16x8 kfr = *(const f16x8a*)(kb + ((n * 2 + ka) << 10) + l * 16);
        acc = __builtin_amdgcn_mfma_f32_16x16x32_f16(kfr, qf[ka], acc, 0, 0, 0);
      }
#pragma unroll
      for (int i = 0; i < 4; ++i) rs += __expf(acc[i] - CSHIFT);
    }
  }
  rs += __shfl_xor(rs, 16);
  rs += __shfl_xor(rs, 32);
  const float inv = 1.0f / rs;

  // ================= loop 2: recompute + attn + PV =================
  f32x4 ctx[4];
#pragma unroll
  for (int n = 0; n < 4; ++n) ctx[n] = (f32x4){0.f, 0.f, 0.f, 0.f};

  for (int kt = 0; kt < NT; ++kt) {
    const char* kb = Kh + ((size_t)kt << 13);
    const char* vb = Vh + ((size_t)kt << 13);
#pragma unroll
    for (int n = 0; n < 4; ++n) {
      f32x4 acc = {0.f, 0.f, 0.f, 0.f};
#pragma unroll
      for (int ka = 0; ka < 2; ++ka) {
        f16x8 kfr = *(const f16x8a*)(kb + ((n * 2 + ka) << 10) + l * 16);
        acc = __builtin_amdgcn_mfma_f32_16x16x32_f16(kfr, qf[ka], acc, 0, 0, 0);
      }
      f32x4 p;
#pragma unroll
      for (int i = 0; i < 4; ++i) p[i] = __expf(acc[i] - CSHIFT) * inv;  // normalized
      f16x4 ph = { (f16)p[0], (f16)p[1], (f16)p[2], (f16)p[3] };
      int slot = (2 * n + (g >> 1)) ^ (c & 7);
      *(f16x4a*)((char*)Pf + (16 * w + c) * 128 + slot * 16 + (g & 1) * 8) = ph;
    }
    // PV: B-frag from Pf (wave-private rows, DS in-order per wave), A-frag
    // from fragment-major Vfg (coalesced b128 global).
#pragma unroll
    for (int ka = 0; ka < 2; ++ka) {
      f16x8 pf = (f16x8)(*(const f16x8a*)((const char*)Pf + (16 * w + c) * 128 + (((4 * ka + g) ^ (c & 7)) << 4)));
#pragma unroll
      for (int n = 0; n < 4; ++n) {
        f16x8 vfr = *(const f16x8a*)(vb + ((n * 2 + ka) << 10) + l * 16);
        ctx[n] = __builtin_amdgcn_mfma_f32_16x16x32_f16(vfr, pf, ctx[n], 0, 0, 0);
      }
    }
    // attn store: b64 LDS read + cvt + nt f32x4; wave covers 4 full rows/inst
    float* abase = attn_h + (size_t)q0 * LL + kt * BK;
#pragma unroll
    for (int it = 0; it < 4; ++it) {
      int r_loc = 16 * w + 4 * it + (l >> 4);
      int u = l & 15;
      int phys = (((u >> 1) ^ (r_loc & 7)) << 4) + (u & 1) * 8;
      f16x4 hv = *(const f16x4a*)((const char*)Pf + r_loc * 128 + phys);
      f32x4 sv = { (float)hv[0], (float)hv[1], (float)hv[2], (float)hv[3] };
      __builtin_nontemporal_store(sv, (f32x4*)(abase + (size_t)r_loc * LL + 4 * u));
    }
  }

#pragma unroll
  for (int n = 0; n < 4; ++n)
    *(f32x4*)(ctx_out + (size_t)(bh * LL + qrow) * DD + n * 16 + 4 * g) = ctx[n];
}

extern "C" void kernel_launch(void* const* d_in, const int* in_sizes, int n_in,
                              void* d_out, int out_size, void* d_ws, size_t ws_size,
                              hipStream_t stream) {
  const float* Q = (const float*)d_in[0];
  const float* K = (const float*)d_in[1];
  const float* V = (const float*)d_in[2];

  float* ctx_out  = (float*)d_out;                      // [32][2048][64]
  float* attn_out = ctx_out + (size_t)NBH * LL * DD;    // [32][2048][2048]

  f16* Kfg = (f16*)d_ws;                                // fragment-major K, 8 MB
  f16* Vfg = Kfg + (size_t)NBH * LL * DD;               // fragment-major V^T, 8 MB

  hipLaunchKernelGGL(prep, dim3(LL / 64, NBH), dim3(256), 0, stream, K, V, Kfg, Vfg);
  hipLaunchKernelGGL(attn_fused, dim3(LL / BQ, NBH), dim3(256), 0, stream,
                     Q, Kfg, Vfg, ctx_out, attn_out);
}